// Round 1
// baseline (3090.360 us; speedup 1.0000x reference)
//
#include <hip/hip_runtime.h>
#include <stdint.h>

typedef __bf16 bf16;
typedef bf16 bf16x8 __attribute__((ext_vector_type(8)));
typedef bf16 bf16x4 __attribute__((ext_vector_type(4)));
typedef float f32x4 __attribute__((ext_vector_type(4)));
typedef uint32_t u32;

#define NN   4096
#define HID  256
#define NCLS 128

__device__ __forceinline__ void gload16(const void* g, void* l) {
  __builtin_amdgcn_global_load_lds((const __attribute__((address_space(1))) u32*)g,
                                   (__attribute__((address_space(3))) u32*)l, 16, 0, 0);
}

// f32 -> bf16 convert, n % 4 == 0
__global__ void convf2b(const float* __restrict__ s, bf16* __restrict__ d, int n) {
  int i = (blockIdx.x * blockDim.x + threadIdx.x) * 4;
  if (i >= n) return;
  f32x4 v = *(const f32x4*)(s + i);
  bf16x4 o;
  #pragma unroll
  for (int j = 0; j < 4; ++j) o[j] = (bf16)v[j];
  *(bf16x4*)(d + i) = o;
}

// Generic 64x64-tile bf16 GEMM: out[m][n] = sum_k A[m][k] * B[n][k]  (+ epilogue)
// EPI: 0=C bf16 (A@y)   1=tanh->bf16 (input L1)   2=h: f32 state + y^T + traj0
//      3..6 = k1..k4 RK4 epilogues   7 = f32 out + bias (output proj)
template<int EPI>
__global__ __launch_bounds__(256) void gemm_k(
    const bf16* __restrict__ Ag, int lda,
    const bf16* __restrict__ Bg, int ldb,
    int Ntiles, int K,
    const float* __restrict__ bias,
    float* __restrict__ outf,
    bf16* __restrict__ outb,
    bf16* __restrict__ ybt,
    float* __restrict__ xbuf,
    const float* __restrict__ kk1,
    const float* __restrict__ kk2,
    const float* __restrict__ kk3,
    const float* __restrict__ vt, int step)
{
  __shared__ __align__(16) char smem[32768]; // 2 bufs x (A 8KB | B 8KB)
  const int tid = threadIdx.x;
  const int l = tid & 63, wv = tid >> 6;
  const int wm = wv >> 1, wn = wv & 1;

  // XCD-aware swizzle: contiguous sb-chunk per XCD -> same A rows stay in one L2
  const int nb = gridDim.x;
  const int chunk = nb >> 3;
  const int sb = (blockIdx.x & 7) * chunk + (blockIdx.x >> 3);
  const int mtile = sb / Ntiles;
  const int ntile = sb - mtile * Ntiles;
  const int m0 = mtile * 64, n0 = ntile * 64;

  // staging: LDS slot (linear) -> pre-swizzled global source (rule #21)
  const int sm = wv * 8 + (l >> 3);                       // row in 32-row half
  const int ck = ((((l & 7) << 4) ^ ((l >> 3) << 4)) >> 1); // swizzled col (elems)
  const bf16* sA = Ag + (size_t)(m0 + sm) * lda + ck;
  const bf16* sB = Bg + (size_t)(n0 + sm) * ldb + ck;

  const int ar = wm * 32 + (l & 15);
  const int br = wn * 32 + (l & 15);
  const int swz = (l & 7) << 4;

  f32x4 acc[2][2] = {{{0.f,0.f,0.f,0.f},{0.f,0.f,0.f,0.f}},
                     {{0.f,0.f,0.f,0.f},{0.f,0.f,0.f,0.f}}};

  auto stage = [&](int buf, int kt) {
    char* base = smem + buf * 16384 + wv * 1024;
    const bf16* a = sA + kt * 64;
    const bf16* b = sB + kt * 64;
    gload16(a,            base);
    gload16(a + 32 * lda, base + 4096);
    gload16(b,            base + 8192);
    gload16(b + 32 * ldb, base + 8192 + 4096);
  };

  auto compute = [&](int buf) {
    const char* As = smem + buf * 16384;
    const char* Bs = As + 8192;
    #pragma unroll
    for (int ks = 0; ks < 2; ++ks) {
      const int kb = ks * 64 + ((l >> 4) << 4);
      const int sw = kb ^ swz;
      bf16x8 a0 = *(const bf16x8*)(As + ar * 128 + sw);
      bf16x8 a1 = *(const bf16x8*)(As + (ar + 16) * 128 + sw);
      bf16x8 b0 = *(const bf16x8*)(Bs + br * 128 + sw);
      bf16x8 b1 = *(const bf16x8*)(Bs + (br + 16) * 128 + sw);
      acc[0][0] = __builtin_amdgcn_mfma_f32_16x16x32_bf16(a0, b0, acc[0][0], 0, 0, 0);
      acc[0][1] = __builtin_amdgcn_mfma_f32_16x16x32_bf16(a0, b1, acc[0][1], 0, 0, 0);
      acc[1][0] = __builtin_amdgcn_mfma_f32_16x16x32_bf16(a1, b0, acc[1][0], 0, 0, 0);
      acc[1][1] = __builtin_amdgcn_mfma_f32_16x16x32_bf16(a1, b1, acc[1][1], 0, 0, 0);
    }
  };

  const int nk = K >> 6;
  stage(0, 0);
  __syncthreads();
  int cur = 0;
  for (int kt = 0; kt < nk; ++kt) {
    if (kt + 1 < nk) stage(cur ^ 1, kt + 1);
    compute(cur);
    __syncthreads();
    cur ^= 1;
  }

  // ---- epilogue ----
  const int r0 = m0 + wm * 32 + ((l >> 4) << 2);
  const int c0 = n0 + wn * 32 + (l & 15);
  float dtv = 0.f;
  if constexpr (EPI >= 3 && EPI <= 6) dtv = vt[step + 1] - vt[step];

  #pragma unroll
  for (int fm = 0; fm < 2; ++fm) {
    #pragma unroll
    for (int fn = 0; fn < 2; ++fn) {
      const int row0 = r0 + fm * 16;
      const int col  = c0 + fn * 16;
      f32x4 a = acc[fm][fn];
      if constexpr (EPI == 0) {
        #pragma unroll
        for (int r = 0; r < 4; ++r) outb[(row0 + r) * HID + col] = (bf16)a[r];
      } else if constexpr (EPI == 1) {
        #pragma unroll
        for (int r = 0; r < 4; ++r)
          outb[(row0 + r) * HID + col] = (bf16)tanhf(a[r] + bias[col]);
      } else if constexpr (EPI == 2) {
        bf16x4 yp;
        #pragma unroll
        for (int r = 0; r < 4; ++r) {
          float v = a[r] + bias[col];
          xbuf[(row0 + r) * HID + col] = v;
          outb[(row0 + r) * HID + col] = (bf16)v;
          yp[r] = (bf16)v;
        }
        *(bf16x4*)(ybt + col * NN + row0) = yp;
      } else if constexpr (EPI >= 3 && EPI <= 6) {
        bf16x4 yp;
        #pragma unroll
        for (int r = 0; r < 4; ++r) {
          const int idx = (row0 + r) * HID + col;
          float v = fmaxf(a[r] + bias[col], 0.f);   // k_p
          float xv = xbuf[idx];
          float y;
          if constexpr (EPI == 3)      { outf[idx] = v; y = xv + dtv * (1.f/3.f) * v; }
          else if constexpr (EPI == 4) { outf[idx] = v; y = xv + dtv * (v - kk1[idx] * (1.f/3.f)); }
          else if constexpr (EPI == 5) { outf[idx] = v; y = xv + dtv * (kk1[idx] - kk2[idx] + v); }
          else { // EPI == 6: k4 -> next state
            float xn = xv + dtv * 0.125f * (kk1[idx] + 3.f*kk2[idx] + 3.f*kk3[idx] + v);
            xbuf[idx] = xn;
            outb[idx] = (bf16)xn;   // traj slot t+1
            y = xn;
          }
          yp[r] = (bf16)y;
        }
        *(bf16x4*)(ybt + col * NN + row0) = yp;   // transposed y for next A@y
      } else { // EPI == 7
        #pragma unroll
        for (int r = 0; r < 4; ++r)
          outf[(size_t)(row0 + r) * NCLS + col] = a[r] + bias[col];
      }
    }
  }
}

extern "C" void kernel_launch(void* const* d_in, const int* in_sizes, int n_in,
                              void* d_out, int out_size, void* d_ws, size_t ws_size,
                              hipStream_t stream)
{
  const float* vt = (const float*)d_in[0];
  const float* x  = (const float*)d_in[1];
  const float* A  = (const float*)d_in[2];
  const float* W1 = (const float*)d_in[3];
  const float* b1 = (const float*)d_in[4];
  const float* W2 = (const float*)d_in[5];
  const float* b2 = (const float*)d_in[6];
  const float* Wt = (const float*)d_in[7];
  const float* bt = (const float*)d_in[8];
  const float* Wo = (const float*)d_in[9];
  const float* bo = (const float*)d_in[10];
  float* out = (float*)d_out;

  char* p = (char*)d_ws;
  auto carve = [&](size_t n) { char* r = p; p += (n + 255) & ~(size_t)255; return r; };
  bf16* Ab  = (bf16*)carve((size_t)4096 * 4096 * 2);
  bf16* xb  = (bf16*)carve((size_t)4096 * 512 * 2);
  bf16* W1b = (bf16*)carve((size_t)256 * 512 * 2);
  bf16* W2b = (bf16*)carve((size_t)256 * 256 * 2);
  bf16* Wtb = (bf16*)carve((size_t)256 * 256 * 2);
  bf16* Wob = (bf16*)carve((size_t)128 * 256 * 2);
  bf16* T1b = (bf16*)carve((size_t)4096 * 256 * 2);
  bf16* Cb  = (bf16*)carve((size_t)4096 * 256 * 2);
  bf16* Yb  = (bf16*)carve((size_t)256 * 4096 * 2);   // y^T [HID][NN]
  float* xs = (float*)carve((size_t)4096 * 256 * 4);  // f32 state
  float* k1 = (float*)carve((size_t)4096 * 256 * 4);
  float* k2 = (float*)carve((size_t)4096 * 256 * 4);
  float* k3 = (float*)carve((size_t)4096 * 256 * 4);
  size_t base_need = (size_t)(p - (char*)d_ws);
  const size_t trajBytes = (size_t)20 * 4096 * 256 * 2;
  bool big = (ws_size >= base_need + trajBytes);
  bf16* traj = (bf16*)carve(big ? trajBytes : (size_t)4096 * 256 * 2);

  convf2b<<<16384, 256, 0, stream>>>(A,  Ab,  16777216);
  convf2b<<<2048,  256, 0, stream>>>(x,  xb,  2097152);
  convf2b<<<128,   256, 0, stream>>>(W1, W1b, 131072);
  convf2b<<<64,    256, 0, stream>>>(W2, W2b, 65536);
  convf2b<<<64,    256, 0, stream>>>(Wt, Wtb, 65536);
  convf2b<<<32,    256, 0, stream>>>(Wo, Wob, 32768);

  // input layer: T1 = tanh(x@W1^T + b1); h = T1@W2^T + b2 -> state, y^T, traj[0]
  gemm_k<1><<<256, 256, 0, stream>>>(xb, 512, W1b, 512, 4, 512, b1,
      nullptr, T1b, nullptr, nullptr, nullptr, nullptr, nullptr, vt, 0);
  gemm_k<2><<<256, 256, 0, stream>>>(T1b, 256, W2b, 256, 4, 256, b2,
      nullptr, traj, Yb, xs, nullptr, nullptr, nullptr, vt, 0);
  if (!big)
    gemm_k<7><<<128, 256, 0, stream>>>(traj, 256, Wob, 256, 2, 256, bo,
        out, nullptr, nullptr, nullptr, nullptr, nullptr, nullptr, vt, 0);

  for (int t = 0; t < 19; ++t) {
    bf16* slot = big ? (traj + (size_t)(t + 1) * 4096 * 256) : traj;
    gemm_k<0><<<256, 256, 0, stream>>>(Ab, 4096, Yb, 4096, 4, 4096, nullptr,
        nullptr, Cb, nullptr, nullptr, nullptr, nullptr, nullptr, vt, 0);
    gemm_k<3><<<256, 256, 0, stream>>>(Cb, 256, Wtb, 256, 4, 256, bt,
        k1, nullptr, Yb, xs, nullptr, nullptr, nullptr, vt, t);
    gemm_k<0><<<256, 256, 0, stream>>>(Ab, 4096, Yb, 4096, 4, 4096, nullptr,
        nullptr, Cb, nullptr, nullptr, nullptr, nullptr, nullptr, vt, 0);
    gemm_k<4><<<256, 256, 0, stream>>>(Cb, 256, Wtb, 256, 4, 256, bt,
        k2, nullptr, Yb, xs, k1, nullptr, nullptr, vt, t);
    gemm_k<0><<<256, 256, 0, stream>>>(Ab, 4096, Yb, 4096, 4, 4096, nullptr,
        nullptr, Cb, nullptr, nullptr, nullptr, nullptr, nullptr, vt, 0);
    gemm_k<5><<<256, 256, 0, stream>>>(Cb, 256, Wtb, 256, 4, 256, bt,
        k3, nullptr, Yb, xs, k1, k2, nullptr, vt, t);
    gemm_k<0><<<256, 256, 0, stream>>>(Ab, 4096, Yb, 4096, 4, 4096, nullptr,
        nullptr, Cb, nullptr, nullptr, nullptr, nullptr, nullptr, vt, 0);
    gemm_k<6><<<256, 256, 0, stream>>>(Cb, 256, Wtb, 256, 4, 256, bt,
        nullptr, slot, Yb, xs, k1, k2, k3, vt, t);
    if (!big)
      gemm_k<7><<<128, 256, 0, stream>>>(traj, 256, Wob, 256, 2, 256, bo,
          out + (size_t)(t + 1) * 4096 * 128, nullptr, nullptr, nullptr,
          nullptr, nullptr, nullptr, vt, 0);
  }
  if (big)
    gemm_k<7><<<2560, 256, 0, stream>>>(traj, 256, Wob, 256, 2, 256, bo,
        out, nullptr, nullptr, nullptr, nullptr, nullptr, nullptr, vt, 0);
}

// Round 2
// 1918.718 us; speedup vs baseline: 1.6106x; 1.6106x over previous
//
#include <hip/hip_runtime.h>
#include <stdint.h>

typedef __bf16 bf16;
typedef bf16 bf16x8 __attribute__((ext_vector_type(8)));
typedef bf16 bf16x4 __attribute__((ext_vector_type(4)));
typedef float f32x4 __attribute__((ext_vector_type(4)));
typedef uint32_t u32;

#define NN   4096
#define HID  256
#define NCLS 128

__device__ __forceinline__ void gload16(const void* g, void* l) {
  __builtin_amdgcn_global_load_lds((const __attribute__((address_space(1))) u32*)g,
                                   (__attribute__((address_space(3))) u32*)l, 16, 0, 0);
}

// f32 -> bf16 convert, n % 4 == 0
__global__ void convf2b(const float* __restrict__ s, bf16* __restrict__ d, int n) {
  int i = (blockIdx.x * blockDim.x + threadIdx.x) * 4;
  if (i >= n) return;
  f32x4 v = *(const f32x4*)(s + i);
  bf16x4 o;
  #pragma unroll
  for (int j = 0; j < 4; ++j) o[j] = (bf16)v[j];
  *(bf16x4*)(d + i) = o;
}

// 64x64-tile bf16 GEMM, 8 waves = 2 spatial (n-halves) x 4 K-split ways.
// Wave tile 64x32 (4x2 frags). 4-deep LDS pipeline, counted vmcnt (T3/T4).
// out[m][n] = sum_k A[m][k]*B[n][k] (+ epilogue).
// EPI: 0=C bf16 (A@y)  1=tanh->bf16  2=h: f32 state + y^T + traj0
//      3..6 = k1..k4 RK4  7 = f32 out + bias
template<int EPI>
__global__ __launch_bounds__(512, 2) void gemm8(
    const bf16* __restrict__ Ag, int lda,
    const bf16* __restrict__ Bg, int ldb,
    int Ntiles, int K,
    const float* __restrict__ bias,
    float* __restrict__ outf,
    bf16* __restrict__ outb,
    bf16* __restrict__ ybt,
    float* __restrict__ xbuf,
    const float* __restrict__ kk1,
    const float* __restrict__ kk2,
    const float* __restrict__ kk3,
    const float* __restrict__ vt, int step)
{
  // 4 bufs x (A 64x128 bf16 = 16KB | B 16KB) = 128 KiB
  __shared__ __align__(16) char smem[131072];
  const int tid = threadIdx.x;
  const int l = tid & 63, wv = tid >> 6;
  const int kw = wv & 3, sw = wv >> 2;       // K-way, spatial n-half
  const int rl = l & 15, hh = l >> 4, sl = l & 7;

  // XCD-aware block swizzle (grid % 8 == 0 everywhere)
  const int nb = gridDim.x;
  const int chunk = nb >> 3;
  const int sb = (blockIdx.x & 7) * chunk + (blockIdx.x >> 3);
  const int mtile = sb / Ntiles;
  const int ntile = sb - mtile * Ntiles;
  const int m0 = mtile * 64, n0 = ntile * 64;

  // ---- staging: wave wv stages 16 rows of A (wv<4) or B (wv>=4) ----
  // LDS layout per tile: row-major [64][128] bf16, 16B chunk c holds global
  // chunk c ^ (row&7)  (both-sides XOR swizzle, rule #21).
  const int srow = (wv & 3) * 16 + hh;
  const bool isB = wv >= 4;
  const size_t ldby = (size_t)(isB ? ldb : lda) * 2;
  const char* sG = (const char*)(isB ? (const void*)(Bg + (size_t)(n0 + srow) * ldb)
                                     : (const void*)(Ag + (size_t)(m0 + srow) * lda));
  const int col0 = (rl ^ (0 + hh)) << 4;   // source col byte, rows R%8==0..3
  const int col4 = (rl ^ (4 + hh)) << 4;   // rows R%8==4..7
  const size_t ld4 = ldby * 4;

  f32x4 acc[4][2];
  #pragma unroll
  for (int i = 0; i < 4; ++i)
    #pragma unroll
    for (int j = 0; j < 2; ++j) acc[i][j] = (f32x4){0.f, 0.f, 0.f, 0.f};

  auto stage = [&](int buf, int t) {
    char* base = smem + buf * 32768 + (isB ? 16384 : 0) + (wv & 3) * 4096;
    const char* g = sG + (size_t)t * 256;    // k-window t*128 elems
    gload16(g + col0,           base);
    gload16(g + ld4 + col4,     base + 1024);
    gload16(g + 2 * ld4 + col0, base + 2048);
    gload16(g + 3 * ld4 + col4, base + 3072);
  };

  const int ca = ((kw * 4 + hh) ^ sl) << 4;  // this wave's swizzled k-chunk
  auto compute = [&](int buf) {
    const char* As = smem + buf * 32768;
    const char* Bs = As + 16384;
    bf16x8 a0 = *(const bf16x8*)(As + (rl +  0) * 256 + ca);
    bf16x8 a1 = *(const bf16x8*)(As + (rl + 16) * 256 + ca);
    bf16x8 a2 = *(const bf16x8*)(As + (rl + 32) * 256 + ca);
    bf16x8 a3 = *(const bf16x8*)(As + (rl + 48) * 256 + ca);
    bf16x8 b0 = *(const bf16x8*)(Bs + (sw * 32 + rl +  0) * 256 + ca);
    bf16x8 b1 = *(const bf16x8*)(Bs + (sw * 32 + rl + 16) * 256 + ca);
    __builtin_amdgcn_s_setprio(1);
    acc[0][0] = __builtin_amdgcn_mfma_f32_16x16x32_bf16(a0, b0, acc[0][0], 0, 0, 0);
    acc[0][1] = __builtin_amdgcn_mfma_f32_16x16x32_bf16(a0, b1, acc[0][1], 0, 0, 0);
    acc[1][0] = __builtin_amdgcn_mfma_f32_16x16x32_bf16(a1, b0, acc[1][0], 0, 0, 0);
    acc[1][1] = __builtin_amdgcn_mfma_f32_16x16x32_bf16(a1, b1, acc[1][1], 0, 0, 0);
    acc[2][0] = __builtin_amdgcn_mfma_f32_16x16x32_bf16(a2, b0, acc[2][0], 0, 0, 0);
    acc[2][1] = __builtin_amdgcn_mfma_f32_16x16x32_bf16(a2, b1, acc[2][1], 0, 0, 0);
    acc[3][0] = __builtin_amdgcn_mfma_f32_16x16x32_bf16(a3, b0, acc[3][0], 0, 0, 0);
    acc[3][1] = __builtin_amdgcn_mfma_f32_16x16x32_bf16(a3, b1, acc[3][1], 0, 0, 0);
    __builtin_amdgcn_s_setprio(0);
  };

  const int nmac = K >> 7;                  // macro K-step = 128
  const int npro = nmac < 3 ? nmac : 3;
  for (int s = 0; s < npro; ++s) stage(s, s);

  for (int t = 0; t < nmac; ++t) {
    const int rem = nmac - 1 - t;
    // wait until this wave's batch-t loads landed; keep newer ones in flight
    if (rem >= 2)      { asm volatile("s_waitcnt vmcnt(8)" ::: "memory"); }
    else if (rem == 1) { asm volatile("s_waitcnt vmcnt(4)" ::: "memory"); }
    else               { asm volatile("s_waitcnt vmcnt(0)" ::: "memory"); }
    __builtin_amdgcn_sched_barrier(0);
    __builtin_amdgcn_s_barrier();
    __builtin_amdgcn_sched_barrier(0);
    if (t + 3 < nmac) stage((t + 3) & 3, t + 3);
    compute(t & 3);
  }
  __builtin_amdgcn_s_barrier();

  // ---- in-block K-split reduce: kw=1..3 dump accs to LDS, kw=0 sums ----
  if (kw != 0) {
    float* dst = (float*)smem + ((kw - 1) * 2 + sw) * 2048;
    #pragma unroll
    for (int mf = 0; mf < 4; ++mf)
      #pragma unroll
      for (int nf = 0; nf < 2; ++nf)
        #pragma unroll
        for (int j = 0; j < 4; ++j)
          dst[(mf * 16 + hh * 4 + j) * 32 + nf * 16 + rl] = acc[mf][nf][j];
  }
  asm volatile("s_waitcnt lgkmcnt(0)" ::: "memory");
  __builtin_amdgcn_s_barrier();
  if (kw != 0) return;

  {
    const float* red = (const float*)smem;
    #pragma unroll
    for (int mf = 0; mf < 4; ++mf)
      #pragma unroll
      for (int nf = 0; nf < 2; ++nf)
        #pragma unroll
        for (int j = 0; j < 4; ++j) {
          const int idx = (mf * 16 + hh * 4 + j) * 32 + nf * 16 + rl;
          acc[mf][nf][j] += red[sw * 2048 + idx] + red[(2 + sw) * 2048 + idx]
                          + red[(4 + sw) * 2048 + idx];
        }
  }

  // ---- epilogue (2 waves: wv 0 and 4) ----
  float dtv = 0.f;
  if constexpr (EPI >= 3 && EPI <= 6) dtv = vt[step + 1] - vt[step];

  #pragma unroll
  for (int mf = 0; mf < 4; ++mf) {
    #pragma unroll
    for (int nf = 0; nf < 2; ++nf) {
      const int row0 = m0 + mf * 16 + hh * 4;
      const int col  = n0 + sw * 32 + nf * 16 + rl;
      f32x4 a = acc[mf][nf];
      if constexpr (EPI == 0) {
        #pragma unroll
        for (int r = 0; r < 4; ++r) outb[(row0 + r) * HID + col] = (bf16)a[r];
      } else if constexpr (EPI == 1) {
        #pragma unroll
        for (int r = 0; r < 4; ++r)
          outb[(row0 + r) * HID + col] = (bf16)tanhf(a[r] + bias[col]);
      } else if constexpr (EPI == 2) {
        bf16x4 yp;
        #pragma unroll
        for (int r = 0; r < 4; ++r) {
          float v = a[r] + bias[col];
          xbuf[(row0 + r) * HID + col] = v;
          outb[(row0 + r) * HID + col] = (bf16)v;
          yp[r] = (bf16)v;
        }
        *(bf16x4*)(ybt + col * NN + row0) = yp;
      } else if constexpr (EPI >= 3 && EPI <= 6) {
        bf16x4 yp;
        #pragma unroll
        for (int r = 0; r < 4; ++r) {
          const int idx = (row0 + r) * HID + col;
          float v = fmaxf(a[r] + bias[col], 0.f);   // k_p
          float xv = xbuf[idx];
          float y;
          if constexpr (EPI == 3)      { outf[idx] = v; y = xv + dtv * (1.f/3.f) * v; }
          else if constexpr (EPI == 4) { outf[idx] = v; y = xv + dtv * (v - kk1[idx] * (1.f/3.f)); }
          else if constexpr (EPI == 5) { outf[idx] = v; y = xv + dtv * (kk1[idx] - kk2[idx] + v); }
          else { // EPI == 6: k4 -> next state
            float xn = xv + dtv * 0.125f * (kk1[idx] + 3.f*kk2[idx] + 3.f*kk3[idx] + v);
            xbuf[idx] = xn;
            outb[idx] = (bf16)xn;   // traj slot t+1
            y = xn;
          }
          yp[r] = (bf16)y;
        }
        *(bf16x4*)(ybt + col * NN + row0) = yp;   // transposed y for next A@y
      } else { // EPI == 7
        #pragma unroll
        for (int r = 0; r < 4; ++r)
          outf[(size_t)(row0 + r) * NCLS + col] = a[r] + bias[col];
      }
    }
  }
}

extern "C" void kernel_launch(void* const* d_in, const int* in_sizes, int n_in,
                              void* d_out, int out_size, void* d_ws, size_t ws_size,
                              hipStream_t stream)
{
  const float* vt = (const float*)d_in[0];
  const float* x  = (const float*)d_in[1];
  const float* A  = (const float*)d_in[2];
  const float* W1 = (const float*)d_in[3];
  const float* b1 = (const float*)d_in[4];
  const float* W2 = (const float*)d_in[5];
  const float* b2 = (const float*)d_in[6];
  const float* Wt = (const float*)d_in[7];
  const float* bt = (const float*)d_in[8];
  const float* Wo = (const float*)d_in[9];
  const float* bo = (const float*)d_in[10];
  float* out = (float*)d_out;

  char* p = (char*)d_ws;
  auto carve = [&](size_t n) { char* r = p; p += (n + 255) & ~(size_t)255; return r; };
  bf16* Ab  = (bf16*)carve((size_t)4096 * 4096 * 2);
  bf16* xb  = (bf16*)carve((size_t)4096 * 512 * 2);
  bf16* W1b = (bf16*)carve((size_t)256 * 512 * 2);
  bf16* W2b = (bf16*)carve((size_t)256 * 256 * 2);
  bf16* Wtb = (bf16*)carve((size_t)256 * 256 * 2);
  bf16* Wob = (bf16*)carve((size_t)128 * 256 * 2);
  bf16* T1b = (bf16*)carve((size_t)4096 * 256 * 2);
  bf16* Cb  = (bf16*)carve((size_t)4096 * 256 * 2);
  bf16* Yb  = (bf16*)carve((size_t)256 * 4096 * 2);   // y^T [HID][NN]
  float* xs = (float*)carve((size_t)4096 * 256 * 4);  // f32 state
  float* k1 = (float*)carve((size_t)4096 * 256 * 4);
  float* k2 = (float*)carve((size_t)4096 * 256 * 4);
  float* k3 = (float*)carve((size_t)4096 * 256 * 4);
  size_t base_need = (size_t)(p - (char*)d_ws);
  const size_t trajBytes = (size_t)20 * 4096 * 256 * 2;
  bool big = (ws_size >= base_need + trajBytes);
  bf16* traj = (bf16*)carve(big ? trajBytes : (size_t)4096 * 256 * 2);

  convf2b<<<16384, 256, 0, stream>>>(A,  Ab,  16777216);
  convf2b<<<2048,  256, 0, stream>>>(x,  xb,  2097152);
  convf2b<<<128,   256, 0, stream>>>(W1, W1b, 131072);
  convf2b<<<64,    256, 0, stream>>>(W2, W2b, 65536);
  convf2b<<<64,    256, 0, stream>>>(Wt, Wtb, 65536);
  convf2b<<<32,    256, 0, stream>>>(Wo, Wob, 32768);

  // input layer: T1 = tanh(x@W1^T + b1); h = T1@W2^T + b2 -> state, y^T, traj[0]
  gemm8<1><<<256, 512, 0, stream>>>(xb, 512, W1b, 512, 4, 512, b1,
      nullptr, T1b, nullptr, nullptr, nullptr, nullptr, nullptr, vt, 0);
  gemm8<2><<<256, 512, 0, stream>>>(T1b, 256, W2b, 256, 4, 256, b2,
      nullptr, traj, Yb, xs, nullptr, nullptr, nullptr, vt, 0);
  if (!big)
    gemm8<7><<<128, 512, 0, stream>>>(traj, 256, Wob, 256, 2, 256, bo,
        out, nullptr, nullptr, nullptr, nullptr, nullptr, nullptr, vt, 0);

  for (int t = 0; t < 19; ++t) {
    bf16* slot = big ? (traj + (size_t)(t + 1) * 4096 * 256) : traj;
    gemm8<0><<<256, 512, 0, stream>>>(Ab, 4096, Yb, 4096, 4, 4096, nullptr,
        nullptr, Cb, nullptr, nullptr, nullptr, nullptr, nullptr, vt, 0);
    gemm8<3><<<256, 512, 0, stream>>>(Cb, 256, Wtb, 256, 4, 256, bt,
        k1, nullptr, Yb, xs, nullptr, nullptr, nullptr, vt, t);
    gemm8<0><<<256, 512, 0, stream>>>(Ab, 4096, Yb, 4096, 4, 4096, nullptr,
        nullptr, Cb, nullptr, nullptr, nullptr, nullptr, nullptr, vt, 0);
    gemm8<4><<<256, 512, 0, stream>>>(Cb, 256, Wtb, 256, 4, 256, bt,
        k2, nullptr, Yb, xs, k1, nullptr, nullptr, vt, t);
    gemm8<0><<<256, 512, 0, stream>>>(Ab, 4096, Yb, 4096, 4, 4096, nullptr,
        nullptr, Cb, nullptr, nullptr, nullptr, nullptr, nullptr, vt, 0);
    gemm8<5><<<256, 512, 0, stream>>>(Cb, 256, Wtb, 256, 4, 256, bt,
        k3, nullptr, Yb, xs, k1, k2, nullptr, vt, t);
    gemm8<0><<<256, 512, 0, stream>>>(Ab, 4096, Yb, 4096, 4, 4096, nullptr,
        nullptr, Cb, nullptr, nullptr, nullptr, nullptr, nullptr, vt, 0);
    gemm8<6><<<256, 512, 0, stream>>>(Cb, 256, Wtb, 256, 4, 256, bt,
        nullptr, slot, Yb, xs, k1, k2, k3, vt, t);
    if (!big)
      gemm8<7><<<128, 512, 0, stream>>>(traj, 256, Wob, 256, 2, 256, bo,
          out + (size_t)(t + 1) * 4096 * 128, nullptr, nullptr, nullptr,
          nullptr, nullptr, nullptr, vt, 0);
  }
  if (big)
    gemm8<7><<<2560, 512, 0, stream>>>(traj, 256, Wob, 256, 2, 256, bo,
        out, nullptr, nullptr, nullptr, nullptr, nullptr, nullptr, vt, 0);
}